// Round 9
// baseline (156.802 us; speedup 1.0000x reference)
//
#include <hip/hip_runtime.h>
#include <hip/hip_cooperative_groups.h>
#include <math.h>
#include <stdint.h>

// Radon forward, MI355X. image (2,1,256,256) fp32 -> out (2,1,363,180) fp32.
// R9: single cooperative kernel (prep phase + grid.sync + main phase) to cut
// one graph-node/dispatch gap; per-sample math identical to R8 (absmax 1.0).
// Phase 1: (a) fp16 quad table q[y][x]={b0:(v00,v01,v10,v11), b1:(...)} 16B,
// 9px zero apron -> ONE dwordx4 gather per (t,c,r) serves both batches
// (apron bound: margin <= 1+2sv+7cv < 9); (b) per-t sincos; (c) per-(t,tile)
// clipped r-range union, int16-packed with union-neutral clamps (R7 bugfix).
// Phase 2: grid-stride over 8280 (t,tile) pairs; 4 waves split each pair's
// r-range; fdot2 bilinear core; LDS reduce.
// Decomposition of dur_us (R4-R8 evidence): ~40.4us harness ws-poison fill
// (83% of achievable HBM - at ITS roofline) + ~15us harness ops/gaps +
// ~12us our kernels. This round attacks dispatch count, the last
// controllable piece. Fallback to the proven R8 two-kernel path if the
// cooperative launch fails.

namespace cg = cooperative_groups;

#define SS 363
#define WW 256
#define NT 180
#define AP 9
#define QDIM (WW + 2 * AP)        // 274
#define QCNT (QDIM * QDIM)        // 75076 records
#define NTILE 46                  // ceil(363/8)
#define NRANGE (NT * NTILE)       // 8280
#define NBQ ((QCNT + 255) / 256)  // 294 quad blocks (fallback path)
#define NBR ((NRANGE + 255) / 256)// 33 range blocks (fallback path)

// ws layout (16B-aligned sections)
#define QOFF 0
#define SCOFF (QCNT * 16)                  // float2 sincos[180]
#define RGOFF (SCOFF + ((NT * 8 + 15) & ~15)) // int packed ranges[8280]
#define WSNEED (RGOFF + NRANGE * 4)

typedef _Float16 h8 __attribute__((ext_vector_type(8)));   // 16 B record
typedef __fp16  h2 __attribute__((ext_vector_type(2)));    // builtin ABI type

#if defined(__has_builtin)
#if __has_builtin(__builtin_amdgcn_fdot2) && __has_builtin(__builtin_amdgcn_cvt_pkrtz)
#define USE_DOT2 1
#endif
#endif

// ---------- shared device helpers (identical math everywhere) ----------
__device__ __forceinline__ void pack_quad(const float* __restrict__ img,
                                          h8* __restrict__ q, int idx) {
    const int iy = idx / QDIM;
    const int ix = idx - iy * QDIM;
    const int y0 = iy - AP, x0 = ix - AP;
    const bool xin0 = ((unsigned)x0 < (unsigned)WW);
    const bool xin1 = ((unsigned)(x0 + 1) < (unsigned)WW);
    const bool yin0 = ((unsigned)y0 < (unsigned)WW);
    const bool yin1 = ((unsigned)(y0 + 1) < (unsigned)WW);
    h8 o;
    #pragma unroll
    for (int b = 0; b < 2; ++b) {
        const float* __restrict__ im = img + b * WW * WW;
        float v00 = 0.f, v01 = 0.f, v10 = 0.f, v11 = 0.f;
        if (yin0) {
            const float* r0 = im + y0 * WW;
            if (xin0) v00 = r0[x0];
            if (xin1) v01 = r0[x0 + 1];
        }
        if (yin1) {
            const float* r1 = im + (y0 + 1) * WW;
            if (xin0) v10 = r1[x0];
            if (xin1) v11 = r1[x0 + 1];
        }
        o[4 * b + 0] = (_Float16)v00;
        o[4 * b + 1] = (_Float16)v01;
        o[4 * b + 2] = (_Float16)v10;
        o[4 * b + 3] = (_Float16)v11;
    }
    q[idx] = o;
}

__device__ __forceinline__ void compute_range(char* __restrict__ ws, int ridx) {
    const int t    = ridx / NTILE;
    const int tile = ridx - t * NTILE;
    float sv, cv;
    sincosf((float)t * 0.017551608191455498f, &sv, &cv);   // t * pi/179
    if (tile == 0) ((float2*)(ws + SCOFF))[t] = make_float2(sv, cv);
    int Ulo = SS, Uhi = -1;                  // empty = (363, -1)
    #pragma unroll
    for (int cl = 0; cl < 8; ++cl) {
        const int c = tile * 8 + cl;
        const float x   = fmaf((float)c, 0.0055248618784530386f, -1.0f);
        const float px0 = fmaf(fmaf(cv, x, -sv), 181.0f, 128.0f);
        const float py0 = fmaf(fmaf(-sv, x, -cv), 181.0f, 128.0f);
        float rlo = 0.0f, rhi = 362.0f;
        if (fabsf(sv) > 1e-8f) {
            const float ra = (-1.0f - px0) / sv, rb = (256.0f - px0) / sv;
            rlo = fmaxf(rlo, fminf(ra, rb)); rhi = fminf(rhi, fmaxf(ra, rb));
        } else if (px0 <= -1.0f || px0 >= 256.0f) rhi = -2.0f;
        if (fabsf(cv) > 1e-8f) {
            const float ra = (-1.0f - py0) / cv, rb = (256.0f - py0) / cv;
            rlo = fmaxf(rlo, fminf(ra, rb)); rhi = fminf(rhi, fmaxf(ra, rb));
        } else if (py0 <= -1.0f || py0 >= 256.0f) rhi = -2.0f;
        // union-neutral int16-safe clamps (R7 bugfix): empty rays -> (363,-1)
        const int Rlo = min(max(0, (int)floorf(rlo) - 1), SS);
        const int Rhi = max(min(SS - 1, (int)ceilf(rhi) + 1), -1);
        Ulo = min(Ulo, Rlo);
        Uhi = max(Uhi, Rhi);
    }
    ((int*)(ws + RGOFF))[ridx] =
        ((int)(unsigned short)(short)Ulo) | ((int)(short)Uhi << 16);
}

// Computes one (t,tile) pair with 4 waves; p0/p1 are the block's LDS slabs.
__device__ __forceinline__ void do_pair(const char* __restrict__ ws,
                                        float* __restrict__ out,
                                        int pair, int tid,
                                        float (*p0)[8], float (*p1)[8]) {
    const int w  = tid >> 6;           // wave 0..3 -> r-range quarter
    const int l  = tid & 63;
    const int cl = l & 7;              // detector bin in tile
    const int rl = l >> 3;             // r sub-lane
    const int t    = pair / NTILE;
    const int tile = pair - t * NTILE;

    const float2 sc = ((const float2*)(ws + SCOFF))[t];
    const float sv = sc.x, cv = sc.y;
    const int rr = ((const int*)(ws + RGOFF))[pair];
    const int Rlo = (int)(short)(rr & 0xffff);
    const int Rhi = rr >> 16;          // arithmetic shift: sign preserved

    const int c = tile * 8 + cl;
    const float x   = fmaf((float)c, 0.0055248618784530386f, -1.0f); // 2/362
    const float px0 = fmaf(fmaf(cv, x, -sv), 181.0f, 128.0f);
    const float py0 = fmaf(fmaf(-sv, x, -cv), 181.0f, 128.0f);

    const uint4* __restrict__ qb = (const uint4*)(ws + QOFF);
    const int base_off = AP * QDIM + AP;
    float acc0 = 0.0f, acc1 = 0.0f;
    #pragma unroll 2
    for (int r = Rlo + rl + 8 * w; r <= Rhi; r += 32) {
        const float rf = (float)r;
        const float px = fmaf(rf, sv, px0);
        const float py = fmaf(rf, cv, py0);
        const float fx = floorf(px), fy = floorf(py);
        const float wx1 = px - fx, wy1 = py - fy;
        const float wx0 = 1.0f - wx1, wy0 = 1.0f - wy1;
        const int idx = (int)fmaf(fy, (float)QDIM, fx) + base_off;
        const uint4 u = qb[idx];
#ifdef USE_DOT2
        const h2 wlo = __builtin_amdgcn_cvt_pkrtz(wy0 * wx0, wy0 * wx1);
        const h2 whi = __builtin_amdgcn_cvt_pkrtz(wy1 * wx0, wy1 * wx1);
        acc0 = __builtin_amdgcn_fdot2(wlo, __builtin_bit_cast(h2, u.x), acc0, false);
        acc0 = __builtin_amdgcn_fdot2(whi, __builtin_bit_cast(h2, u.y), acc0, false);
        acc1 = __builtin_amdgcn_fdot2(wlo, __builtin_bit_cast(h2, u.z), acc1, false);
        acc1 = __builtin_amdgcn_fdot2(whi, __builtin_bit_cast(h2, u.w), acc1, false);
#else
        const h2 v01 = __builtin_bit_cast(h2, u.x);
        const h2 v23 = __builtin_bit_cast(h2, u.y);
        const h2 v45 = __builtin_bit_cast(h2, u.z);
        const h2 v67 = __builtin_bit_cast(h2, u.w);
        const float top0 = fmaf(wx0, (float)v01[0], wx1 * (float)v01[1]);
        const float bot0 = fmaf(wx0, (float)v23[0], wx1 * (float)v23[1]);
        acc0 = fmaf(wy0, top0, acc0);
        acc0 = fmaf(wy1, bot0, acc0);
        const float top1 = fmaf(wx0, (float)v45[0], wx1 * (float)v45[1]);
        const float bot1 = fmaf(wx0, (float)v67[0], wx1 * (float)v67[1]);
        acc1 = fmaf(wy0, top1, acc1);
        acc1 = fmaf(wy1, bot1, acc1);
#endif
    }
    acc0 += __shfl_xor(acc0, 8, 64);
    acc0 += __shfl_xor(acc0, 16, 64);
    acc0 += __shfl_xor(acc0, 32, 64);
    acc1 += __shfl_xor(acc1, 8, 64);
    acc1 += __shfl_xor(acc1, 16, 64);
    acc1 += __shfl_xor(acc1, 32, 64);

    if (l < 8) { p0[w][l] = acc0; p1[w][l] = acc1; }
    __syncthreads();
    if (tid < 8) {
        const int cc = tile * 8 + tid;
        if (cc < SS) {
            out[(0 * SS + cc) * NT + t] =
                p0[0][tid] + p0[1][tid] + p0[2][tid] + p0[3][tid];
            out[(1 * SS + cc) * NT + t] =
                p1[0][tid] + p1[1][tid] + p1[2][tid] + p1[3][tid];
        }
    }
    __syncthreads();   // protect LDS before next pair reuses it
}

// ---------- R9 fused cooperative kernel ----------
#define FUSED_BLOCKS 1024          // 4 blocks/CU (16 waves/CU) — co-resident

__global__ __launch_bounds__(256, 4) void radon_fused(const float* __restrict__ img,
                                                      char* __restrict__ ws,
                                                      float* __restrict__ out) {
    const int tid  = threadIdx.x;
    const int gidx = blockIdx.x * 256 + tid;
    // Phase 1 (no early returns — every thread must reach grid.sync)
    if (gidx < QCNT) {
        pack_quad(img, (h8*)(ws + QOFF), gidx);
    } else if (gidx < QCNT + NRANGE) {
        compute_range(ws, gidx - QCNT);
    }
    cg::this_grid().sync();
    // Phase 2: grid-stride over (t,tile) pairs
    __shared__ float p0[4][8], p1[4][8];
    for (int pair = blockIdx.x; pair < NRANGE; pair += FUSED_BLOCKS)
        do_pair(ws, out, pair, tid, p0, p1);
}

// ---------- R8 two-kernel fallback (if cooperative launch fails) ----------
__global__ __launch_bounds__(256) void radon_prep(const float* __restrict__ img,
                                                  char* __restrict__ ws) {
    if (blockIdx.x < NBQ) {
        const int idx = blockIdx.x * 256 + threadIdx.x;
        if (idx >= QCNT) return;
        pack_quad(img, (h8*)(ws + QOFF), idx);
    } else {
        const int ridx = (blockIdx.x - NBQ) * 256 + threadIdx.x;
        if (ridx >= NRANGE) return;
        compute_range(ws, ridx);
    }
}

__global__ __launch_bounds__(256) void radon_main(const char* __restrict__ ws,
                                                  float* __restrict__ out) {
    __shared__ float p0[4][8], p1[4][8];
    do_pair(ws, out, blockIdx.y * NTILE + blockIdx.x, threadIdx.x, p0, p1);
}

// ---- R2-style fallback (only if ws_size can't hold the tables) ----
__global__ __launch_bounds__(256) void radon_fwd_fb(const float* __restrict__ img,
                                                    float* __restrict__ out) {
    const int tid = threadIdx.x;
    const int w = tid >> 6, l = tid & 63, cl = l & 7, rl = l >> 3;
    const int c0 = blockIdx.x * 8, c = c0 + cl, t = blockIdx.y, b = blockIdx.z;
    float sv, cv;
    sincosf((float)t * 0.017551608191455498f, &sv, &cv);
    const float x   = fmaf((float)c, 0.0055248618784530386f, -1.0f);
    const float px0 = fmaf(fmaf(cv, x, -sv), 181.0f, 128.0f);
    const float py0 = fmaf(fmaf(-sv, x, -cv), 181.0f, 128.0f);
    float rlo = 0.0f, rhi = 362.0f;
    if (fabsf(sv) > 1e-8f) {
        const float ra = (-1.0f - px0) / sv, rb = (256.0f - px0) / sv;
        rlo = fmaxf(rlo, fminf(ra, rb)); rhi = fminf(rhi, fmaxf(ra, rb));
    } else if (px0 <= -1.0f || px0 >= 256.0f) rhi = -2.0f;
    if (fabsf(cv) > 1e-8f) {
        const float ra = (-1.0f - py0) / cv, rb = (256.0f - py0) / cv;
        rlo = fmaxf(rlo, fminf(ra, rb)); rhi = fminf(rhi, fmaxf(ra, rb));
    } else if (py0 <= -1.0f || py0 >= 256.0f) rhi = -2.0f;
    int Rlo = max(0, (int)floorf(rlo) - 1);
    int Rhi = min(SS - 1, (int)ceilf(rhi) + 1);
    #pragma unroll
    for (int o = 1; o <= 4; o <<= 1) {
        Rlo = min(Rlo, __shfl_xor(Rlo, o, 64));
        Rhi = max(Rhi, __shfl_xor(Rhi, o, 64));
    }
    const float* __restrict__ imgb = img + b * (WW * WW);
    float acc = 0.0f;
    for (int r = Rlo + 8 * w + rl; r <= Rhi; r += 32) {
        const float rf = (float)r;
        const float px = fmaf(rf, sv, px0), py = fmaf(rf, cv, py0);
        const float fx = floorf(px), fy = floorf(py);
        float wx1 = px - fx, wy1 = py - fy;
        float wx0 = 1.0f - wx1, wy0 = 1.0f - wy1;
        const int x0 = (int)fx, y0 = (int)fy, x1 = x0 + 1, y1 = y0 + 1;
        wx0 *= ((unsigned)x0 < (unsigned)WW) ? 1.0f : 0.0f;
        wx1 *= ((unsigned)x1 < (unsigned)WW) ? 1.0f : 0.0f;
        wy0 *= ((unsigned)y0 < (unsigned)WW) ? 1.0f : 0.0f;
        wy1 *= ((unsigned)y1 < (unsigned)WW) ? 1.0f : 0.0f;
        const int xc0 = min(max(x0, 0), WW - 1), xc1 = min(max(x1, 0), WW - 1);
        const int yc0 = min(max(y0, 0), WW - 1), yc1 = min(max(y1, 0), WW - 1);
        const float* r0p = imgb + yc0 * WW;
        const float* r1p = imgb + yc1 * WW;
        const float top = fmaf(wx0, r0p[xc0], wx1 * r0p[xc1]);
        const float bot = fmaf(wx0, r1p[xc0], wx1 * r1p[xc1]);
        acc = fmaf(wy0, top, acc);
        acc = fmaf(wy1, bot, acc);
    }
    acc += __shfl_xor(acc, 8, 64);
    acc += __shfl_xor(acc, 16, 64);
    acc += __shfl_xor(acc, 32, 64);
    __shared__ float part[4][8];
    if (l < 8) part[w][l] = acc;
    __syncthreads();
    if (tid < 8) {
        const int cc = c0 + tid;
        if (cc < SS)
            out[(b * SS + cc) * NT + t] =
                part[0][tid] + part[1][tid] + part[2][tid] + part[3][tid];
    }
}

extern "C" void kernel_launch(void* const* d_in, const int* in_sizes, int n_in,
                              void* d_out, int out_size, void* d_ws, size_t ws_size,
                              hipStream_t stream) {
    (void)in_sizes; (void)n_in; (void)out_size;
    const float* img = (const float*)d_in[0];
    float* out = (float*)d_out;
    if (ws_size >= (size_t)WSNEED) {
        char* ws = (char*)d_ws;
        void* args[3] = {(void*)&img, (void*)&ws, (void*)&out};
        hipError_t e = hipLaunchCooperativeKernel((void*)radon_fused,
                                                  dim3(FUSED_BLOCKS), dim3(256),
                                                  args, 0, stream);
        if (e != hipSuccess) {
            // proven R8 two-kernel path
            hipLaunchKernelGGL(radon_prep, dim3(NBQ + NBR), dim3(256), 0,
                               stream, img, ws);
            hipLaunchKernelGGL(radon_main, dim3(NTILE, NT, 1), dim3(256), 0,
                               stream, ws, out);
        }
    } else {
        dim3 grid((SS + 7) / 8, NT, 2);
        hipLaunchKernelGGL(radon_fwd_fb, grid, dim3(256), 0, stream, img, out);
    }
}

// Round 10
// 71.893 us; speedup vs baseline: 2.1811x; 2.1811x over previous
//
#include <hip/hip_runtime.h>
#include <math.h>
#include <stdint.h>

// Radon forward, MI355X. image (2,1,256,256) fp32 -> out (2,1,363,180) fp32.
// R10 = exact revert to R8 (best: 71.93us, absmax 1.0). R9's cooperative
// fusion regressed to 156us: grid.sync() on 1024 blocks costs ~90us on
// gfx950 (cross-XCD device-scope barrier forces L2 writeback — FETCH/WRITE
// jumped 2080->5490 / 2047->3289 KB) and caps occupancy at 43%. Two plain
// dispatches with an implicit dependency are far cheaper.
// Structure: prep fills (a) fp16 quad table q[y][x] = {b0 corners, b1
// corners} 16B with 9px zero apron (one dwordx4 gather per (t,c,r) serves
// both batches; apron bound: margin <= 1+2sv+7cv < 9), (b) per-t sincos,
// (c) per-(t,tile) clipped r-range (int16-packed, union-neutral clamps).
// Main: block = (t,tile), 4 waves split the r-range (max wave work 12
// iters), preamble = 2 uniform loads, fdot2 bilinear core, LDS reduce.
// Timed-region decomposition (R4-R9 evidence): ~40.4us harness ws-poison
// fill (83% of achievable HBM - at ITS roofline) + ~15us fixed harness
// restore/replay overhead + ~12us our two kernels (latency/launch bound:
// VALUBusy and HBM% both negligible at their scale).

#define SS 363
#define WW 256
#define NT 180
#define AP 9
#define QDIM (WW + 2 * AP)        // 274
#define QCNT (QDIM * QDIM)        // 75076 records
#define NTILE 46                  // ceil(363/8)
#define NRANGE (NT * NTILE)       // 8280
#define NBQ ((QCNT + 255) / 256)  // 294 quad blocks
#define NBR ((NRANGE + 255) / 256)// 33 range blocks

// ws layout (16B-aligned sections)
#define QOFF 0
#define SCOFF (QCNT * 16)                  // float2 sincos[180]
#define RGOFF (SCOFF + ((NT * 8 + 15) & ~15)) // int packed ranges[8280]
#define WSNEED (RGOFF + NRANGE * 4)

typedef _Float16 h8 __attribute__((ext_vector_type(8)));   // 16 B record
typedef __fp16  h2 __attribute__((ext_vector_type(2)));    // builtin ABI type

#if defined(__has_builtin)
#if __has_builtin(__builtin_amdgcn_fdot2) && __has_builtin(__builtin_amdgcn_cvt_pkrtz)
#define USE_DOT2 1
#endif
#endif

__global__ __launch_bounds__(256) void radon_prep(const float* __restrict__ img,
                                                  char* __restrict__ ws) {
    h8* __restrict__ q = (h8*)(ws + QOFF);
    if (blockIdx.x < NBQ) {
        const int idx = blockIdx.x * 256 + threadIdx.x;
        if (idx >= QCNT) return;
        const int iy = idx / QDIM;
        const int ix = idx - iy * QDIM;
        const int y0 = iy - AP, x0 = ix - AP;
        const bool xin0 = ((unsigned)x0 < (unsigned)WW);
        const bool xin1 = ((unsigned)(x0 + 1) < (unsigned)WW);
        const bool yin0 = ((unsigned)y0 < (unsigned)WW);
        const bool yin1 = ((unsigned)(y0 + 1) < (unsigned)WW);
        h8 o;
        #pragma unroll
        for (int b = 0; b < 2; ++b) {
            const float* __restrict__ im = img + b * WW * WW;
            float v00 = 0.f, v01 = 0.f, v10 = 0.f, v11 = 0.f;
            if (yin0) {
                const float* r0 = im + y0 * WW;
                if (xin0) v00 = r0[x0];
                if (xin1) v01 = r0[x0 + 1];
            }
            if (yin1) {
                const float* r1 = im + (y0 + 1) * WW;
                if (xin0) v10 = r1[x0];
                if (xin1) v11 = r1[x0 + 1];
            }
            o[4 * b + 0] = (_Float16)v00;
            o[4 * b + 1] = (_Float16)v01;
            o[4 * b + 2] = (_Float16)v10;
            o[4 * b + 3] = (_Float16)v11;
        }
        q[idx] = o;
    } else {
        // per-(t,tile) conservative clip-range union + per-t sincos table.
        // Clip math replicated EXACTLY from the R4/R6 main preamble.
        const int ridx = (blockIdx.x - NBQ) * 256 + threadIdx.x;
        if (ridx >= NRANGE) return;
        const int t    = ridx / NTILE;
        const int tile = ridx - t * NTILE;
        float sv, cv;
        sincosf((float)t * 0.017551608191455498f, &sv, &cv);   // t * pi/179
        if (tile == 0) ((float2*)(ws + SCOFF))[t] = make_float2(sv, cv);
        int Ulo = SS;            // empty = (363, -1)
        int Uhi = -1;
        #pragma unroll
        for (int cl = 0; cl < 8; ++cl) {
            const int c = tile * 8 + cl;
            const float x   = fmaf((float)c, 0.0055248618784530386f, -1.0f);
            const float px0 = fmaf(fmaf(cv, x, -sv), 181.0f, 128.0f);
            const float py0 = fmaf(fmaf(-sv, x, -cv), 181.0f, 128.0f);
            float rlo = 0.0f, rhi = 362.0f;
            if (fabsf(sv) > 1e-8f) {
                const float ra = (-1.0f - px0) / sv, rb = (256.0f - px0) / sv;
                rlo = fmaxf(rlo, fminf(ra, rb)); rhi = fminf(rhi, fmaxf(ra, rb));
            } else if (px0 <= -1.0f || px0 >= 256.0f) rhi = -2.0f;
            if (fabsf(cv) > 1e-8f) {
                const float ra = (-1.0f - py0) / cv, rb = (256.0f - py0) / cv;
                rlo = fmaxf(rlo, fminf(ra, rb)); rhi = fminf(rhi, fmaxf(ra, rb));
            } else if (py0 <= -1.0f || py0 >= 256.0f) rhi = -2.0f;
            // clamp to int16-safe, union-neutral bounds (R7 bugfix):
            // empty rays (rlo>rhi, possibly |.|~1e7 at near-degenerate t)
            // collapse to (363,-1) and cannot affect the union.
            const int Rlo = min(max(0, (int)floorf(rlo) - 1), SS);
            const int Rhi = max(min(SS - 1, (int)ceilf(rhi) + 1), -1);
            Ulo = min(Ulo, Rlo);
            Uhi = max(Uhi, Rhi);
        }
        // pack as two signed int16: Ulo in [0,363], Uhi in [-1,362]
        ((int*)(ws + RGOFF))[ridx] =
            ((int)(unsigned short)(short)Ulo) | ((int)(short)Uhi << 16);
    }
}

__global__ __launch_bounds__(256) void radon_main(const char* __restrict__ ws,
                                                  float* __restrict__ out) {
    const int tid = threadIdx.x;
    const int w   = tid >> 6;          // wave 0..3 -> r-range quarter
    const int l   = tid & 63;
    const int cl  = l & 7;             // detector bin in tile
    const int rl  = l >> 3;            // r sub-lane
    const int tile = blockIdx.x;
    const int t    = blockIdx.y;

    const float2 sc = ((const float2*)(ws + SCOFF))[t];
    const float sv = sc.x, cv = sc.y;
    const int rr = ((const int*)(ws + RGOFF))[t * NTILE + tile];
    const int Rlo = (int)(short)(rr & 0xffff);
    const int Rhi = rr >> 16;          // arithmetic shift: sign preserved

    const int c = tile * 8 + cl;
    const float x   = fmaf((float)c, 0.0055248618784530386f, -1.0f); // 2/362
    const float px0 = fmaf(fmaf(cv, x, -sv), 181.0f, 128.0f);
    const float py0 = fmaf(fmaf(-sv, x, -cv), 181.0f, 128.0f);
    // apron safety: r in tile union -> generating ray c' has px' in
    // (-1-2sv, 256+2sv); |px-px'| <= 7|cv| -> margin <= 1+2sv+7cv <= 8.29 < 9.

    const uint4* __restrict__ qb = (const uint4*)(ws + QOFF);
    const int base_off = AP * QDIM + AP;          // apron fold (constant)
    float acc0 = 0.0f, acc1 = 0.0f;
    #pragma unroll 2
    for (int r = Rlo + rl + 8 * w; r <= Rhi; r += 32) {
        const float rf = (float)r;
        const float px = fmaf(rf, sv, px0);
        const float py = fmaf(rf, cv, py0);
        const float fx = floorf(px), fy = floorf(py);
        const float wx1 = px - fx, wy1 = py - fy;
        const float wx0 = 1.0f - wx1, wy0 = 1.0f - wy1;
        // fy*274+fx is an exact integer in fp32 (|fy|<=273): one cvt total
        const int idx = (int)fmaf(fy, (float)QDIM, fx) + base_off;
        const uint4 u = qb[idx];
#ifdef USE_DOT2
        const h2 wlo = __builtin_amdgcn_cvt_pkrtz(wy0 * wx0, wy0 * wx1);
        const h2 whi = __builtin_amdgcn_cvt_pkrtz(wy1 * wx0, wy1 * wx1);
        acc0 = __builtin_amdgcn_fdot2(wlo, __builtin_bit_cast(h2, u.x), acc0, false);
        acc0 = __builtin_amdgcn_fdot2(whi, __builtin_bit_cast(h2, u.y), acc0, false);
        acc1 = __builtin_amdgcn_fdot2(wlo, __builtin_bit_cast(h2, u.z), acc1, false);
        acc1 = __builtin_amdgcn_fdot2(whi, __builtin_bit_cast(h2, u.w), acc1, false);
#else
        const h2 v01 = __builtin_bit_cast(h2, u.x);
        const h2 v23 = __builtin_bit_cast(h2, u.y);
        const h2 v45 = __builtin_bit_cast(h2, u.z);
        const h2 v67 = __builtin_bit_cast(h2, u.w);
        const float top0 = fmaf(wx0, (float)v01[0], wx1 * (float)v01[1]);
        const float bot0 = fmaf(wx0, (float)v23[0], wx1 * (float)v23[1]);
        acc0 = fmaf(wy0, top0, acc0);
        acc0 = fmaf(wy1, bot0, acc0);
        const float top1 = fmaf(wx0, (float)v45[0], wx1 * (float)v45[1]);
        const float bot1 = fmaf(wx0, (float)v67[0], wx1 * (float)v67[1]);
        acc1 = fmaf(wy0, top1, acc1);
        acc1 = fmaf(wy1, bot1, acc1);
#endif
    }
    acc0 += __shfl_xor(acc0, 8, 64);
    acc0 += __shfl_xor(acc0, 16, 64);
    acc0 += __shfl_xor(acc0, 32, 64);
    acc1 += __shfl_xor(acc1, 8, 64);
    acc1 += __shfl_xor(acc1, 16, 64);
    acc1 += __shfl_xor(acc1, 32, 64);

    __shared__ float p0[4][8], p1[4][8];
    if (l < 8) { p0[w][l] = acc0; p1[w][l] = acc1; }
    __syncthreads();
    if (tid < 8) {
        const int cc = tile * 8 + tid;
        if (cc < SS) {
            out[(0 * SS + cc) * NT + t] =
                p0[0][tid] + p0[1][tid] + p0[2][tid] + p0[3][tid];
            out[(1 * SS + cc) * NT + t] =
                p1[0][tid] + p1[1][tid] + p1[2][tid] + p1[3][tid];
        }
    }
}

// ---- R2-style fallback (only if ws_size can't hold the tables) ----
__global__ __launch_bounds__(256) void radon_fwd_fb(const float* __restrict__ img,
                                                    float* __restrict__ out) {
    const int tid = threadIdx.x;
    const int w = tid >> 6, l = tid & 63, cl = l & 7, rl = l >> 3;
    const int c0 = blockIdx.x * 8, c = c0 + cl, t = blockIdx.y, b = blockIdx.z;
    float sv, cv;
    sincosf((float)t * 0.017551608191455498f, &sv, &cv);
    const float x   = fmaf((float)c, 0.0055248618784530386f, -1.0f);
    const float px0 = fmaf(fmaf(cv, x, -sv), 181.0f, 128.0f);
    const float py0 = fmaf(fmaf(-sv, x, -cv), 181.0f, 128.0f);
    float rlo = 0.0f, rhi = 362.0f;
    if (fabsf(sv) > 1e-8f) {
        const float ra = (-1.0f - px0) / sv, rb = (256.0f - px0) / sv;
        rlo = fmaxf(rlo, fminf(ra, rb)); rhi = fminf(rhi, fmaxf(ra, rb));
    } else if (px0 <= -1.0f || px0 >= 256.0f) rhi = -2.0f;
    if (fabsf(cv) > 1e-8f) {
        const float ra = (-1.0f - py0) / cv, rb = (256.0f - py0) / cv;
        rlo = fmaxf(rlo, fminf(ra, rb)); rhi = fminf(rhi, fmaxf(ra, rb));
    } else if (py0 <= -1.0f || py0 >= 256.0f) rhi = -2.0f;
    int Rlo = max(0, (int)floorf(rlo) - 1);
    int Rhi = min(SS - 1, (int)ceilf(rhi) + 1);
    #pragma unroll
    for (int o = 1; o <= 4; o <<= 1) {
        Rlo = min(Rlo, __shfl_xor(Rlo, o, 64));
        Rhi = max(Rhi, __shfl_xor(Rhi, o, 64));
    }
    const float* __restrict__ imgb = img + b * (WW * WW);
    float acc = 0.0f;
    for (int r = Rlo + 8 * w + rl; r <= Rhi; r += 32) {
        const float rf = (float)r;
        const float px = fmaf(rf, sv, px0), py = fmaf(rf, cv, py0);
        const float fx = floorf(px), fy = floorf(py);
        float wx1 = px - fx, wy1 = py - fy;
        float wx0 = 1.0f - wx1, wy0 = 1.0f - wy1;
        const int x0 = (int)fx, y0 = (int)fy, x1 = x0 + 1, y1 = y0 + 1;
        wx0 *= ((unsigned)x0 < (unsigned)WW) ? 1.0f : 0.0f;
        wx1 *= ((unsigned)x1 < (unsigned)WW) ? 1.0f : 0.0f;
        wy0 *= ((unsigned)y0 < (unsigned)WW) ? 1.0f : 0.0f;
        wy1 *= ((unsigned)y1 < (unsigned)WW) ? 1.0f : 0.0f;
        const int xc0 = min(max(x0, 0), WW - 1), xc1 = min(max(x1, 0), WW - 1);
        const int yc0 = min(max(y0, 0), WW - 1), yc1 = min(max(y1, 0), WW - 1);
        const float* r0p = imgb + yc0 * WW;
        const float* r1p = imgb + yc1 * WW;
        const float top = fmaf(wx0, r0p[xc0], wx1 * r0p[xc1]);
        const float bot = fmaf(wx0, r1p[xc0], wx1 * r1p[xc1]);
        acc = fmaf(wy0, top, acc);
        acc = fmaf(wy1, bot, acc);
    }
    acc += __shfl_xor(acc, 8, 64);
    acc += __shfl_xor(acc, 16, 64);
    acc += __shfl_xor(acc, 32, 64);
    __shared__ float part[4][8];
    if (l < 8) part[w][l] = acc;
    __syncthreads();
    if (tid < 8) {
        const int cc = c0 + tid;
        if (cc < SS)
            out[(b * SS + cc) * NT + t] =
                part[0][tid] + part[1][tid] + part[2][tid] + part[3][tid];
    }
}

extern "C" void kernel_launch(void* const* d_in, const int* in_sizes, int n_in,
                              void* d_out, int out_size, void* d_ws, size_t ws_size,
                              hipStream_t stream) {
    (void)in_sizes; (void)n_in; (void)out_size;
    const float* img = (const float*)d_in[0];
    float* out = (float*)d_out;
    if (ws_size >= (size_t)WSNEED) {
        char* ws = (char*)d_ws;
        hipLaunchKernelGGL(radon_prep, dim3(NBQ + NBR), dim3(256), 0,
                           stream, img, ws);
        dim3 grid(NTILE, NT, 1);               // 46 x 180 blocks
        hipLaunchKernelGGL(radon_main, grid, dim3(256), 0, stream, ws, out);
    } else {
        dim3 grid((SS + 7) / 8, NT, 2);
        hipLaunchKernelGGL(radon_fwd_fb, grid, dim3(256), 0, stream, img, out);
    }
}